// Round 6
// baseline (274.586 us; speedup 1.0000x reference)
//
#include <hip/hip_runtime.h>

typedef unsigned int u32;
typedef unsigned short u16;
typedef unsigned long long ull;

constexpr int kB = 16, kT = 16, kN = 184, kD = 128, kH = 8, kHD = 16;
constexpr int kBT = kB * kT;            // 256
constexpr int kRows = kBT * kN;         // 47104
constexpr int kTile = kN * kHD;         // 2944 elements per (hb,t) tile
// softmax scale folded into q at projection: 0.25 * log2(e)
#define KQSCALE 0.36067376022224085f

typedef __attribute__((ext_vector_type(8))) short bf16x8;
typedef __attribute__((ext_vector_type(4))) float f32x4;

union FragU {
  bf16x8 f;
  ull u[2];
  uint4 q;
  u16 h[8];
};

#define MFMA(a, b, c) __builtin_amdgcn_mfma_f32_16x16x32_bf16((a), (b), (c), 0, 0, 0)

__device__ __forceinline__ float bf2f(u16 v) {
  return __uint_as_float(((u32)v) << 16);
}
__device__ __forceinline__ u16 f2bf(float f) {
  u32 x = __float_as_uint(f);
  x += 0x7fffu + ((x >> 16) & 1u);   // RNE
  return (u16)(x >> 16);
}
// pack two fp32 -> two bf16 (RNE) in one u32: lo in [15:0], hi in [31:16]
__device__ __forceinline__ u32 pack_bf2(float lo, float hi) {
  u32 a = __float_as_uint(lo); a += 0x7fffu + ((a >> 16) & 1u);
  u32 b = __float_as_uint(hi); b += 0x7fffu + ((b >> 16) & 1u);
  return __builtin_amdgcn_perm(b, a, 0x07060302);
}
// pack two fp32 -> two bf16 (truncate) in one u32 — single v_perm
__device__ __forceinline__ u32 pack_trunc(float lo, float hi) {
  return __builtin_amdgcn_perm(__float_as_uint(hi), __float_as_uint(lo), 0x07060302);
}
__device__ __forceinline__ u16 trunc_bf(float f) {
  return (u16)(__float_as_uint(f) >> 16);
}

// ---------------------------------------------------------------------------
// Kernel 1: adp softmax fragments + (r13) weight fp32->bf16 conversion merged
// (was a separate wcvt_kernel launch). Grid 12; conversion and phase 2 are
// block-strided; phase 1 redundant per block.
// ---------------------------------------------------------------------------
__global__ __launch_bounds__(256) void adp_kernel(
    const float* __restrict__ ne1, const float* __restrict__ ne2,
    u16* __restrict__ arr3, u16* __restrict__ arr4,
    const float* __restrict__ Wq, const float* __restrict__ Wk,
    const float* __restrict__ Wv, const float* __restrict__ Wo,
    u16* __restrict__ wb) {
  __shared__ float s1[kN * 10];
  __shared__ float s2[10 * kN];
  __shared__ float l1r[kN];
  __shared__ float l2c[kN];
  const int tid = threadIdx.x;

  // ---- weight conversion (block-strided over 8192 u32-pairs)
  {
    u32* dst = (u32*)wb;
    for (int t = blockIdx.x * 256 + tid; t < 8192; t += 12 * 256) {
      float2 a = ((const float2*)Wq)[t]; dst[t]          = pack_bf2(a.x, a.y);
      float2 b = ((const float2*)Wk)[t]; dst[8192 + t]   = pack_bf2(b.x, b.y);
      float2 c = ((const float2*)Wv)[t]; dst[16384 + t]  = pack_bf2(c.x, c.y);
      float2 d = ((const float2*)Wo)[t]; dst[24576 + t]  = pack_bf2(d.x, d.y);
    }
  }

  for (int i = tid; i < kN * 10; i += 256) { s1[i] = ne1[i]; s2[i] = ne2[i]; }
  __syncthreads();

  if (tid < kN) {
    const int r = tid;
    float reg[10];
#pragma unroll
    for (int e = 0; e < 10; ++e) reg[e] = s1[r * 10 + e];
    float sum = 0.f;
    for (int c = 0; c < kN; ++c) {
      float d = 0.f;
#pragma unroll
      for (int e = 0; e < 10; ++e) d += reg[e] * s2[e * kN + c];
      sum += __expf(d);
    }
    l1r[r] = sum;

    const int c = tid;
    float regc[10];
#pragma unroll
    for (int e = 0; e < 10; ++e) regc[e] = s2[e * kN + c];
    sum = 0.f;
    for (int r2 = 0; r2 < kN; ++r2) {
      float d = 0.f;
#pragma unroll
      for (int e = 0; e < 10; ++e) d += s1[r2 * 10 + e] * regc[e];
      sum += __expf(d);
    }
    l2c[c] = sum;
  }
  __syncthreads();

  for (int ee = blockIdx.x * 256 + tid; ee < 12 * 6 * 64; ee += 12 * 256) {
    const int i = ee / 384;
    const int rem = ee - i * 384;
    const int p = rem >> 6;
    const int lane = rem & 63;
    const int row = i * 16 + (lane & 15);
    const int cb = p * 32 + (lane >> 4) * 8;
    FragU fo3, fo4;
    const bool rok = row < kN;
    float inv1 = 0.f, inv2 = 0.f;
    float rreg[10], creg[10];
    if (rok) {
      inv1 = 1.f / l1r[row];
      inv2 = 1.f / l2c[row];
#pragma unroll
      for (int e = 0; e < 10; ++e) {
        rreg[e] = s1[row * 10 + e];
        creg[e] = s2[e * kN + row];
      }
    }
#pragma unroll
    for (int j = 0; j < 8; ++j) {
      const int col = cb + j;
      float v3 = 0.f, v4 = 0.f;
      if (rok && col < kN) {
        float d3 = 0.f, d4 = 0.f;
#pragma unroll
        for (int e = 0; e < 10; ++e) {
          d3 += rreg[e] * s2[e * kN + col];
          d4 += s1[col * 10 + e] * creg[e];
        }
        v3 = __expf(d3) * inv1;
        v4 = __expf(d4) * inv2;
      }
      fo3.h[j] = f2bf(v3);
      fo4.h[j] = f2bf(v4);
    }
    *(uint4*)(arr3 + (size_t)ee * 8) = fo3.q;
    *(uint4*)(arr4 + (size_t)ee * 8) = fo4.q;
  }
}

// ---------------------------------------------------------------------------
// Kernel 2: MFMA projection GEMM (r12 version, unchanged). q pre-scaled.
// ---------------------------------------------------------------------------
__global__ __launch_bounds__(256) void proj_kernel(
    const float* __restrict__ qin, const float* __restrict__ kin, const float* __restrict__ vin,
    const u16* __restrict__ wb,
    const float* __restrict__ bq, const float* __restrict__ bk, const float* __restrict__ bv,
    u16* __restrict__ qo, u16* __restrict__ ko, u16* __restrict__ vo) {
  __shared__ u16 s_w[128 * 136];
  __shared__ u16 s_a[128 * 136];

  const float* in; const u16* W; const float* bias; u16* out; float scale;
  if (blockIdx.y == 0)      { in = qin; W = wb;         bias = bq; out = qo; scale = KQSCALE; }
  else if (blockIdx.y == 1) { in = kin; W = wb + 16384; bias = bk; out = ko; scale = 1.f; }
  else                      { in = vin; W = wb + 32768; bias = bv; out = vo; scale = 1.f; }

  const int tid = threadIdx.x;
  const int r0 = blockIdx.x * 128;
  {
    const uint4* src = (const uint4*)W;
    for (int i = tid; i < 2048; i += 256) {
      const int row = i >> 4, q16 = i & 15;
      *(uint4*)(s_w + row * 136 + q16 * 8) = src[i];
    }
    const float* abase = in + (size_t)r0 * 128;
#pragma unroll
    for (int i = 0; i < 16; ++i) {
      const int idx = i * 1024 + tid * 4;
      const float4 v = *(const float4*)(abase + idx);
      const int row = idx >> 7, col = idx & 127;
      *(u32*)(s_a + row * 136 + col)     = pack_bf2(v.x, v.y);
      *(u32*)(s_a + row * 136 + col + 2) = pack_bf2(v.z, v.w);
    }
  }
  __syncthreads();

  const int w = tid >> 6, lane = tid & 63, quad = lane >> 4, m = lane & 15;

  f32x4 acc0[8], acc1[8];
  const f32x4 z4 = {0.f, 0.f, 0.f, 0.f};
#pragma unroll
  for (int ct = 0; ct < 8; ++ct) { acc0[ct] = z4; acc1[ct] = z4; }

  const u16* ap0 = s_a + (w * 16 + m) * 136 + quad * 8;
  const u16* ap1 = ap0 + 64 * 136;

#pragma unroll
  for (int kp = 0; kp < 4; ++kp) {
    FragU a0; a0.q = *(const uint4*)(ap0 + kp * 32);
    FragU a1; a1.q = *(const uint4*)(ap1 + kp * 32);
#pragma unroll
    for (int ct = 0; ct < 8; ++ct) {
      FragU bfr; bfr.q = *(const uint4*)(s_w + (ct * 16 + m) * 136 + kp * 32 + quad * 8);
      acc0[ct] = MFMA(a0.f, bfr.f, acc0[ct]);
      acc1[ct] = MFMA(a1.f, bfr.f, acc1[ct]);
    }
  }

  float bc[8];
#pragma unroll
  for (int ct = 0; ct < 8; ++ct) bc[ct] = bias[ct * 16 + m];

#pragma unroll
  for (int half = 0; half < 2; ++half) {
    const f32x4* acc = half ? acc1 : acc0;
    const int rbase = r0 + (w + half * 4) * 16 + quad * 4;
#pragma unroll
    for (int rr = 0; rr < 4; ++rr) {
      const int r = rbase + rr;
      const int bt = r / kN;
      const int n = r - bt * kN;
      u16* op = out + ((size_t)bt * kN + n) * 16 + m;
#pragma unroll
      for (int ct = 0; ct < 8; ++ct)
        op[(size_t)ct * kBT * kN * 16] = f2bf((acc[ct][rr] + bc[ct]) * scale);
    }
  }
}

// ---------------------------------------------------------------------------
// Kernel 3: MFMA dual-softmax attention + adp mixing + fused Wm.
// r13: swapped S-work assignment — wave w owns k-tile w of each chunk x ALL
// 12 q-tiles (MFMA(A=kOwn[c], B=qAll[qt])). Consequences:
//  * The wave's S output IS the ET rows its own COL pass reads -> ET is
//    per-wave PRIVATE [16][200] (single buffer, no barrier, no dbuf).
//  * s_E [192][72] becomes the cross-wave buffer (ROW pass reads all waves'
//    k-columns) -> S phases are barrier-isolated from fat {COL,ROW} phases.
//  * LDS 78,848 -> 53,248 B = 3 blocks/CU (12 waves, +50% TLP).
//  * 7 barriers: bar_a (vT), bar_a2 (vb reads before S'0 clobbers vT alias),
//    and S'0|b|F0|b|S'1|b|F1|b|S'2|b|F2. cat aliases own-ET (wave-local,
//    program-order safe after COL2); vT aliases s_E region.
// Per-wave op counts identical to r11; all LDS access patterns bit-identical
// in structure (b64 E-row write, b16 ET scatter, b128 reads).
// ---------------------------------------------------------------------------
__global__ __launch_bounds__(256, 3) void attn_kernel(
    const u16* qg, const u16* __restrict__ kg, const u16* __restrict__ vg,
    const u16* __restrict__ arr3, const u16* __restrict__ arr4,
    const float* __restrict__ Wm, const float* __restrict__ bm,
    u16* mg) {
  __shared__ u16 pool[26624];            // 53,248 B
  u16* const s_E  = pool;                // [192][72]  (13824 elems, cross-wave)
  u16* const s_ET = pool + 13824;        // 4 x [16][200] per-wave (12800 elems)
  u16* const s_vT = pool;                // alias s_E region: [16][200]

  const int tid = threadIdx.x;
  const size_t base = (size_t)blockIdx.x * kTile;
  const int w = tid >> 6, lane = tid & 63;
  const int quad = lane >> 4, m = lane & 15;
  u16* const ET_w = s_ET + w * 3200;     // this wave's private ET

  // ---- stage V transposed into s_vT (= s_E region; dead after vb reads)
  for (int idx = tid; idx < 3072; idx += 256) {
    const int t = idx >> 4, ch = idx & 15;
    s_vT[ch * 200 + t] = (t < kN) ? vg[base + idx] : (u16)0;
  }

  // ---- own K A-fragments: k-tiles {w, w+4, w+8} (chunk-local ktl = w).
  bf16x8 kOwn[3];
#pragma unroll
  for (int c = 0; c < 3; ++c) {
    FragU fk; fk.u[0] = 0; fk.u[1] = 0;
    const int tok = (c * 4 + w) * 16 + m;
    if (quad < 2 && tok < kN)
      fk.q = *(const uint4*)(kg + base + tok * 16 + quad * 8);
    kOwn[c] = fk.f;
  }
  // ---- ALL 12 q B-fragments.
  bf16x8 qAll[12];
#pragma unroll
  for (int t12 = 0; t12 < 12; ++t12) {
    FragU fq; fq.u[0] = 0; fq.u[1] = 0;
    const int tok = t12 * 16 + m;
    if (quad < 2 && tok < kN)
      fq.q = *(const uint4*)(qg + base + tok * 16 + quad * 8);
    qAll[t12] = fq.f;
  }

  // ---- Wm A-fragments with interleaved cat-dim mapping (unchanged).
  bf16x8 wmb[2];
#pragma unroll
  for (int kt = 0; kt < 2; ++kt) {
    FragU f;
#pragma unroll
    for (int j = 0; j < 8; ++j) {
      const int kdl = quad * 8 + j;
      const int orig = (kt * 2 + (kdl & 1)) * 16 + (kdl >> 1);
      f.h[j] = f2bf(Wm[m * 64 + orig]);
    }
    wmb[kt] = f.f;
  }
  const float4 bm4 = *(const float4*)(bm + quad * 4);

  __syncthreads();   // bar_a: vT staged; all qg reads drained (mg aliases qg)

  bf16x8 vb[6];   // V B-frags
#pragma unroll
  for (int p = 0; p < 6; ++p) {
    FragU f;
    f.q = *(const uint4*)(s_vT + m * 200 + p * 32 + quad * 8);
    vb[p] = f.f;
  }
  __syncthreads();   // bar_a2: all vb reads done before S'0 clobbers vT alias

  FragU onesU; onesU.u[0] = 0x3F803F803F803F80ULL; onesU.u[1] = onesU.u[0];
  const bf16x8 ones = onesU.f;
  const f32x4 zero4 = {0.f, 0.f, 0.f, 0.f};

  f32x4 o1[3], l1[3], o3[3], o4[3], o2[3], l2[3];
#pragma unroll
  for (int ti = 0; ti < 3; ++ti) {
    o1[ti] = zero4; l1[ti] = zero4; o3[ti] = zero4;
    o4[ti] = zero4; o2[ti] = zero4; l2[ti] = zero4;
  }

  // S_PHASE(CC): wave computes S for its own k-tile (CC*4+w) x all 12 q-tiles.
  // D lane(m,quad) reg r = S[q=qt*16+m][k=(CC*4+w)*16+quad*4+r].
  // Writes: s_E[(qt*16+m)*72 + w*16+quad*4] (b64) and own-ET rows quad*4+r.
#define S_PHASE(CC)                                                           \
  do {                                                                        \
    _Pragma("unroll") for (int qt = 0; qt < 12; ++qt) {                       \
      f32x4 sv = MFMA(kOwn[CC], qAll[qt], zero4);                             \
      const float e0 = exp2f(sv[0]), e1 = exp2f(sv[1]);                       \
      const float e2 = exp2f(sv[2]), e3 = exp2f(sv[3]);                       \
      uint2 evv;                                                              \
      evv.x = pack_trunc(e0, e1);                                             \
      evv.y = pack_trunc(e2, e3);                                             \
      *(uint2*)(s_E + (qt * 16 + m) * 72 + w * 16 + quad * 4) = evv;          \
      u16* etp = ET_w + (quad * 4) * 200 + qt * 16 + m;                       \
      etp[0]   = trunc_bf(e0);                                                \
      etp[200] = trunc_bf(e1);                                                \
      etp[400] = trunc_bf(e2);                                                \
      etp[600] = trunc_bf(e3);                                                \
    }                                                                         \
  } while (0)

#define LOAD_ARR(CC)                                                          \
  _Pragma("unroll") for (int ti = 0; ti < 3; ++ti) {                          \
    const int qt = w + ti * 4;                                                \
    _Pragma("unroll") for (int pl = 0; pl < 2; ++pl) {                        \
      const int pg = (CC) * 2 + pl;                                           \
      a3f[ti * 2 + pl].q = *(const uint4*)(arr3 + (size_t)((qt * 6 + pg) * 64 + lane) * 8); \
      a4f[ti * 2 + pl].q = *(const uint4*)(arr4 + (size_t)((qt * 6 + pg) * 64 + lane) * 8); \
    }                                                                         \
  }

  // ROW_PHASE(CC): o1/l1/o3/o4 for own q-tiles; s_E reads are CROSS-WAVE
  // (sealed by the barrier before this interval).
#define ROW_PHASE(CC)                                                         \
  _Pragma("unroll") for (int ti = 0; ti < 3; ++ti) {                          \
    const int qt = w + ti * 4;                                                \
    const u16* erp = s_E + (qt * 16 + m) * 72 + quad * 8;                     \
    _Pragma("unroll") for (int pl = 0; pl < 2; ++pl) {                        \
      const int pg = (CC) * 2 + pl;                                           \
      FragU pa; pa.q = *(const uint4*)(erp + pl * 32);                        \
      o1[ti] = MFMA(pa.f, vb[pg], o1[ti]);                                    \
      l1[ti] = MFMA(pa.f, ones, l1[ti]);                                      \
      o3[ti] = MFMA(a3f[ti * 2 + pl].f, vb[pg], o3[ti]);                      \
      o4[ti] = MFMA(a4f[ti * 2 + pl].f, vb[pg], o4[ti]);                      \
    }                                                                         \
  }

  // COL_PHASE(CC): reads OWN private ET (wave-local; no barrier needed).
  // Output key tile = CC*4+w, matching epilogue tt = w + CC*4.
#define COL_PHASE(CC)                                                         \
  {                                                                           \
    const u16* etr = ET_w + m * 200 + quad * 8;                               \
    _Pragma("unroll") for (int pg = 0; pg < 6; ++pg) {                        \
      FragU pT; pT.q = *(const uint4*)(etr + pg * 32);                        \
      o2[CC] = MFMA(pT.f, vb[pg], o2[CC]);                                    \
      l2[CC] = MFMA(pT.f, ones, l2[CC]);                                      \
    }                                                                         \
  }

  S_PHASE(0);
  __syncthreads();
  {
    FragU a3f[6], a4f[6];
    LOAD_ARR(0);
    COL_PHASE(0);
    ROW_PHASE(0);
  }
  __syncthreads();
  S_PHASE(1);
  __syncthreads();
  {
    FragU a3f[6], a4f[6];
    LOAD_ARR(1);
    COL_PHASE(1);
    ROW_PHASE(1);
  }
  __syncthreads();
  S_PHASE(2);
  __syncthreads();
  {
    FragU a3f[6], a4f[6];
    LOAD_ARR(2);
    COL_PHASE(2);
    ROW_PHASE(2);
  }

#undef S_PHASE
#undef LOAD_ARR
#undef ROW_PHASE
#undef COL_PHASE

  // ================= fused Wm epilogue (cat aliases own-ET; wave-local,
  // program-order after COL2's last own-ET read — no barrier needed) =======
  u16* cw = ET_w;
#pragma unroll
  for (int ti = 0; ti < 3; ++ti) {
    const int tt = w + ti * 4;
#pragma unroll
    for (int r = 0; r < 4; ++r) {
      const int token = quad * 4 + r;
      const float n1 = o1[ti][r] * __builtin_amdgcn_rcpf(l1[ti][r] - 8.0f);
      const float n2 = o2[ti][r] * __builtin_amdgcn_rcpf(l2[ti][r] - 8.0f);
      *(u32*)(cw + token * 72 + 2 * m)      = pack_bf2(n1, n2);       // dims 2m,2m+1
      *(u32*)(cw + token * 72 + 32 + 2 * m) = pack_bf2(o3[ti][r], o4[ti][r]);
    }
    f32x4 macc = {bm4.x, bm4.y, bm4.z, bm4.w};
#pragma unroll
    for (int kt = 0; kt < 2; ++kt) {
      FragU ca; ca.q = *(const uint4*)(cw + m * 72 + kt * 32 + quad * 8);
      macc = MFMA(wmb[kt], ca.f, macc);   // filt^T = Wm @ cat^T
    }
    if (tt * 16 + m < kN) {
      *(uint2*)(mg + base + (tt * 16 + m) * 16 + quad * 4) =
          make_uint2(pack_bf2(macc[0], macc[1]), pack_bf2(macc[2], macc[3]));
    }
  }
}

// ---------------------------------------------------------------------------
// Kernel 4: MFMA head-merge + Wo GEMM, fp32 out + bo (unchanged).
// ---------------------------------------------------------------------------
__global__ __launch_bounds__(256) void out_kernel(
    const u16* __restrict__ mg, const u16* __restrict__ wob,
    const float* __restrict__ bo, float* __restrict__ outg) {
  __shared__ u16 s_w[128 * 136];
  const int tid = threadIdx.x;
  {
    const uint4* src = (const uint4*)wob;
    for (int i = tid; i < 2048; i += 256) {
      const int row = i >> 4, q16 = i & 15;
      *(uint4*)(s_w + row * 136 + q16 * 8) = src[i];
    }
  }
  __syncthreads();

  const int w = tid >> 6, lane = tid & 63, quad = lane >> 4, m = lane & 15;
  const int r0 = blockIdx.x * 128;

  f32x4 acc0[8], acc1[8];
  const f32x4 z4 = {0.f, 0.f, 0.f, 0.f};
#pragma unroll
  for (int ct = 0; ct < 8; ++ct) { acc0[ct] = z4; acc1[ct] = z4; }

  const int hh = quad >> 1, hd8 = (quad & 1) * 8;
  const int ra = r0 + w * 16 + m;
  const int bt0 = ra / kN, n0 = ra - bt0 * kN;
  const int rb = ra + 64;
  const int bt1 = rb / kN, n1 = rb - bt1 * kN;
  const u16* mp0 = mg + ((size_t)(hh * kBT + bt0) * kN + n0) * 16 + hd8;
  const u16* mp1 = mg + ((size_t)(hh * kBT + bt1) * kN + n1) * 16 + hd8;
  const size_t hstep = (size_t)2 * kBT * kN * 16;

#pragma unroll
  for (int kp = 0; kp < 4; ++kp) {
    FragU a0; a0.q = *(const uint4*)(mp0 + kp * hstep);
    FragU a1; a1.q = *(const uint4*)(mp1 + kp * hstep);
#pragma unroll
    for (int ct = 0; ct < 8; ++ct) {
      FragU bfr; bfr.q = *(const uint4*)(s_w + (ct * 16 + m) * 136 + kp * 32 + quad * 8);
      acc0[ct] = MFMA(a0.f, bfr.f, acc0[ct]);
      acc1[ct] = MFMA(a1.f, bfr.f, acc1[ct]);
    }
  }

  float bc[8];
#pragma unroll
  for (int ct = 0; ct < 8; ++ct) bc[ct] = bo[ct * 16 + m];

#pragma unroll
  for (int half = 0; half < 2; ++half) {
    const f32x4* acc = half ? acc1 : acc0;
    const int rbase = r0 + (w + half * 4) * 16 + quad * 4;
#pragma unroll
    for (int rr = 0; rr < 4; ++rr) {
      float* op = outg + (size_t)(rbase + rr) * 128 + m;
#pragma unroll
      for (int ct = 0; ct < 8; ++ct)
        op[ct * 16] = acc[ct][rr] + bc[ct];
    }
  }
}

// ---------------------------------------------------------------------------
extern "C" void kernel_launch(void* const* d_in, const int* in_sizes, int n_in,
                              void* d_out, int out_size, void* d_ws, size_t ws_size,
                              hipStream_t stream) {
  const float* query = (const float*)d_in[0];
  const float* key   = (const float*)d_in[1];
  const float* value = (const float*)d_in[2];
  const float* Wq = (const float*)d_in[3];
  const float* bq = (const float*)d_in[4];
  const float* Wk = (const float*)d_in[5];
  const float* bk = (const float*)d_in[6];
  const float* Wv = (const float*)d_in[7];
  const float* bv = (const float*)d_in[8];
  const float* Wm = (const float*)d_in[9];
  const float* bm = (const float*)d_in[10];
  const float* Wo = (const float*)d_in[11];
  const float* bo = (const float*)d_in[12];
  const float* ne1 = (const float*)d_in[13];
  const float* ne2 = (const float*)d_in[14];

  const size_t tensor_bytes = (size_t)kH * kB * kT * kN * kHD * 2;  // 12,058,624
  const size_t frag_bytes = (size_t)12 * 6 * 64 * 8 * 2;            // 73,728
  char* ws = (char*)d_ws;
  u16* qs   = (u16*)(ws);                        // reused as m after attn
  u16* ks   = (u16*)(ws + tensor_bytes);
  u16* vs   = (u16*)(ws + 2 * tensor_bytes);
  u16* arr3 = (u16*)(ws + 3 * tensor_bytes);
  u16* arr4 = (u16*)(ws + 3 * tensor_bytes + frag_bytes);
  u16* wb   = (u16*)(ws + 3 * tensor_bytes + 2 * frag_bytes);  // 4x16384 bf16

  adp_kernel<<<12, 256, 0, stream>>>(ne1, ne2, arr3, arr4, Wq, Wk, Wv, Wo, wb);
  proj_kernel<<<dim3(kRows / 128, 3), 256, 0, stream>>>(
      query, key, value, wb, bq, bk, bv, qs, ks, vs);
  attn_kernel<<<kH * kB * kT, 256, 0, stream>>>(qs, ks, vs, arr3, arr4, Wm, bm, qs);
  out_kernel<<<kRows / 128, 256, 0, stream>>>(qs, wb + 49152, bo, (float*)d_out);
}

// Round 7
// 269.331 us; speedup vs baseline: 1.0195x; 1.0195x over previous
//
#include <hip/hip_runtime.h>

typedef unsigned int u32;
typedef unsigned short u16;
typedef unsigned long long ull;

constexpr int kB = 16, kT = 16, kN = 184, kD = 128, kH = 8, kHD = 16;
constexpr int kBT = kB * kT;            // 256
constexpr int kRows = kBT * kN;         // 47104
constexpr int kTile = kN * kHD;         // 2944 elements per (hb,t) tile
// softmax scale folded into q at projection: 0.25 * log2(e)
#define KQSCALE 0.36067376022224085f

typedef __attribute__((ext_vector_type(8))) short bf16x8;
typedef __attribute__((ext_vector_type(4))) float f32x4;

union FragU {
  bf16x8 f;
  ull u[2];
  uint4 q;
  u16 h[8];
};

#define MFMA(a, b, c) __builtin_amdgcn_mfma_f32_16x16x32_bf16((a), (b), (c), 0, 0, 0)

__device__ __forceinline__ float bf2f(u16 v) {
  return __uint_as_float(((u32)v) << 16);
}
__device__ __forceinline__ u16 f2bf(float f) {
  u32 x = __float_as_uint(f);
  x += 0x7fffu + ((x >> 16) & 1u);   // RNE
  return (u16)(x >> 16);
}
// pack two fp32 -> two bf16 (RNE) in one u32: lo in [15:0], hi in [31:16]
__device__ __forceinline__ u32 pack_bf2(float lo, float hi) {
  u32 a = __float_as_uint(lo); a += 0x7fffu + ((a >> 16) & 1u);
  u32 b = __float_as_uint(hi); b += 0x7fffu + ((b >> 16) & 1u);
  return __builtin_amdgcn_perm(b, a, 0x07060302);
}
// pack two fp32 -> two bf16 (truncate) in one u32 — single v_perm
__device__ __forceinline__ u32 pack_trunc(float lo, float hi) {
  return __builtin_amdgcn_perm(__float_as_uint(hi), __float_as_uint(lo), 0x07060302);
}
__device__ __forceinline__ u16 trunc_bf(float f) {
  return (u16)(__float_as_uint(f) >> 16);
}

// ---------------------------------------------------------------------------
// Kernel 1: adp softmax fragments + weight fp32->bf16 conversion merged.
// Grid 12; conversion and phase 2 block-strided; phase 1 redundant per block.
// ---------------------------------------------------------------------------
__global__ __launch_bounds__(256) void adp_kernel(
    const float* __restrict__ ne1, const float* __restrict__ ne2,
    u16* __restrict__ arr3, u16* __restrict__ arr4,
    const float* __restrict__ Wq, const float* __restrict__ Wk,
    const float* __restrict__ Wv, const float* __restrict__ Wo,
    u16* __restrict__ wb) {
  __shared__ float s1[kN * 10];
  __shared__ float s2[10 * kN];
  __shared__ float l1r[kN];
  __shared__ float l2c[kN];
  const int tid = threadIdx.x;

  // ---- weight conversion (block-strided over 8192 u32-pairs)
  {
    u32* dst = (u32*)wb;
    for (int t = blockIdx.x * 256 + tid; t < 8192; t += 12 * 256) {
      float2 a = ((const float2*)Wq)[t]; dst[t]          = pack_bf2(a.x, a.y);
      float2 b = ((const float2*)Wk)[t]; dst[8192 + t]   = pack_bf2(b.x, b.y);
      float2 c = ((const float2*)Wv)[t]; dst[16384 + t]  = pack_bf2(c.x, c.y);
      float2 d = ((const float2*)Wo)[t]; dst[24576 + t]  = pack_bf2(d.x, d.y);
    }
  }

  for (int i = tid; i < kN * 10; i += 256) { s1[i] = ne1[i]; s2[i] = ne2[i]; }
  __syncthreads();

  if (tid < kN) {
    const int r = tid;
    float reg[10];
#pragma unroll
    for (int e = 0; e < 10; ++e) reg[e] = s1[r * 10 + e];
    float sum = 0.f;
    for (int c = 0; c < kN; ++c) {
      float d = 0.f;
#pragma unroll
      for (int e = 0; e < 10; ++e) d += reg[e] * s2[e * kN + c];
      sum += __expf(d);
    }
    l1r[r] = sum;

    const int c = tid;
    float regc[10];
#pragma unroll
    for (int e = 0; e < 10; ++e) regc[e] = s2[e * kN + c];
    sum = 0.f;
    for (int r2 = 0; r2 < kN; ++r2) {
      float d = 0.f;
#pragma unroll
      for (int e = 0; e < 10; ++e) d += s1[r2 * 10 + e] * regc[e];
      sum += __expf(d);
    }
    l2c[c] = sum;
  }
  __syncthreads();

  for (int ee = blockIdx.x * 256 + tid; ee < 12 * 6 * 64; ee += 12 * 256) {
    const int i = ee / 384;
    const int rem = ee - i * 384;
    const int p = rem >> 6;
    const int lane = rem & 63;
    const int row = i * 16 + (lane & 15);
    const int cb = p * 32 + (lane >> 4) * 8;
    FragU fo3, fo4;
    const bool rok = row < kN;
    float inv1 = 0.f, inv2 = 0.f;
    float rreg[10], creg[10];
    if (rok) {
      inv1 = 1.f / l1r[row];
      inv2 = 1.f / l2c[row];
#pragma unroll
      for (int e = 0; e < 10; ++e) {
        rreg[e] = s1[row * 10 + e];
        creg[e] = s2[e * kN + row];
      }
    }
#pragma unroll
    for (int j = 0; j < 8; ++j) {
      const int col = cb + j;
      float v3 = 0.f, v4 = 0.f;
      if (rok && col < kN) {
        float d3 = 0.f, d4 = 0.f;
#pragma unroll
        for (int e = 0; e < 10; ++e) {
          d3 += rreg[e] * s2[e * kN + col];
          d4 += s1[col * 10 + e] * creg[e];
        }
        v3 = __expf(d3) * inv1;
        v4 = __expf(d4) * inv2;
      }
      fo3.h[j] = f2bf(v3);
      fo4.h[j] = f2bf(v4);
    }
    *(uint4*)(arr3 + (size_t)ee * 8) = fo3.q;
    *(uint4*)(arr4 + (size_t)ee * 8) = fo4.q;
  }
}

// ---------------------------------------------------------------------------
// Kernel 2: MFMA projection GEMM (r12 version, unchanged). q pre-scaled.
// ---------------------------------------------------------------------------
__global__ __launch_bounds__(256) void proj_kernel(
    const float* __restrict__ qin, const float* __restrict__ kin, const float* __restrict__ vin,
    const u16* __restrict__ wb,
    const float* __restrict__ bq, const float* __restrict__ bk, const float* __restrict__ bv,
    u16* __restrict__ qo, u16* __restrict__ ko, u16* __restrict__ vo) {
  __shared__ u16 s_w[128 * 136];
  __shared__ u16 s_a[128 * 136];

  const float* in; const u16* W; const float* bias; u16* out; float scale;
  if (blockIdx.y == 0)      { in = qin; W = wb;         bias = bq; out = qo; scale = KQSCALE; }
  else if (blockIdx.y == 1) { in = kin; W = wb + 16384; bias = bk; out = ko; scale = 1.f; }
  else                      { in = vin; W = wb + 32768; bias = bv; out = vo; scale = 1.f; }

  const int tid = threadIdx.x;
  const int r0 = blockIdx.x * 128;
  {
    const uint4* src = (const uint4*)W;
    for (int i = tid; i < 2048; i += 256) {
      const int row = i >> 4, q16 = i & 15;
      *(uint4*)(s_w + row * 136 + q16 * 8) = src[i];
    }
    const float* abase = in + (size_t)r0 * 128;
#pragma unroll
    for (int i = 0; i < 16; ++i) {
      const int idx = i * 1024 + tid * 4;
      const float4 v = *(const float4*)(abase + idx);
      const int row = idx >> 7, col = idx & 127;
      *(u32*)(s_a + row * 136 + col)     = pack_bf2(v.x, v.y);
      *(u32*)(s_a + row * 136 + col + 2) = pack_bf2(v.z, v.w);
    }
  }
  __syncthreads();

  const int w = tid >> 6, lane = tid & 63, quad = lane >> 4, m = lane & 15;

  f32x4 acc0[8], acc1[8];
  const f32x4 z4 = {0.f, 0.f, 0.f, 0.f};
#pragma unroll
  for (int ct = 0; ct < 8; ++ct) { acc0[ct] = z4; acc1[ct] = z4; }

  const u16* ap0 = s_a + (w * 16 + m) * 136 + quad * 8;
  const u16* ap1 = ap0 + 64 * 136;

#pragma unroll
  for (int kp = 0; kp < 4; ++kp) {
    FragU a0; a0.q = *(const uint4*)(ap0 + kp * 32);
    FragU a1; a1.q = *(const uint4*)(ap1 + kp * 32);
#pragma unroll
    for (int ct = 0; ct < 8; ++ct) {
      FragU bfr; bfr.q = *(const uint4*)(s_w + (ct * 16 + m) * 136 + kp * 32 + quad * 8);
      acc0[ct] = MFMA(a0.f, bfr.f, acc0[ct]);
      acc1[ct] = MFMA(a1.f, bfr.f, acc1[ct]);
    }
  }

  float bc[8];
#pragma unroll
  for (int ct = 0; ct < 8; ++ct) bc[ct] = bias[ct * 16 + m];

#pragma unroll
  for (int half = 0; half < 2; ++half) {
    const f32x4* acc = half ? acc1 : acc0;
    const int rbase = r0 + (w + half * 4) * 16 + quad * 4;
#pragma unroll
    for (int rr = 0; rr < 4; ++rr) {
      const int r = rbase + rr;
      const int bt = r / kN;
      const int n = r - bt * kN;
      u16* op = out + ((size_t)bt * kN + n) * 16 + m;
#pragma unroll
      for (int ct = 0; ct < 8; ++ct)
        op[(size_t)ct * kBT * kN * 16] = f2bf((acc[ct][rr] + bc[ct]) * scale);
    }
  }
}

// ---------------------------------------------------------------------------
// Kernel 3: MFMA dual-softmax attention + adp mixing + fused Wm.
// r14 = r13 structure (wave owns k-tile w per chunk x all q-tiles; private
// ET, cross-wave s_E, 53,248 B LDS, 3 blocks/CU) with the SPILL fixed:
//  * q B-fragments are NOT kept live across the kernel — loaded from global
//    inside S_PHASE right before use (q tile 5.9 KB/block, L2-hot re-read;
//    mg/qg may-alias so compiler preserves load-before-epilogue-store order;
//    cross-block tiles disjoint).  -48 long-lived VGPRs.
//  * arr3/arr4 fragments loaded inline per (ti,pl) in ROW_PHASE (latency
//    hidden by 12 waves/CU TLP).  -48 staging VGPRs.
// Long-lived set: kOwn 12 + vb 24 + wmb 8 + acc 72 + bm4 ~= 120 -> fits the
// (256,3) cap (~170) without scratch. r13's 250 MB/dispatch spill traffic
// (WRITE_SIZE 158 MB vs 12 MB of real output) should collapse.
// ---------------------------------------------------------------------------
__global__ __launch_bounds__(256, 3) void attn_kernel(
    const u16* qg, const u16* __restrict__ kg, const u16* __restrict__ vg,
    const u16* __restrict__ arr3, const u16* __restrict__ arr4,
    const float* __restrict__ Wm, const float* __restrict__ bm,
    u16* mg) {
  __shared__ u16 pool[26624];            // 53,248 B
  u16* const s_E  = pool;                // [192][72]  (13824 elems, cross-wave)
  u16* const s_ET = pool + 13824;        // 4 x [16][200] per-wave (12800 elems)
  u16* const s_vT = pool;                // alias s_E region: [16][200]

  const int tid = threadIdx.x;
  const size_t base = (size_t)blockIdx.x * kTile;
  const int w = tid >> 6, lane = tid & 63;
  const int quad = lane >> 4, m = lane & 15;
  u16* const ET_w = s_ET + w * 3200;     // this wave's private ET

  // ---- stage V transposed into s_vT (= s_E region; dead after vb reads)
  for (int idx = tid; idx < 3072; idx += 256) {
    const int t = idx >> 4, ch = idx & 15;
    s_vT[ch * 200 + t] = (t < kN) ? vg[base + idx] : (u16)0;
  }

  // ---- own K A-fragments: k-tiles {w, w+4, w+8} (chunk-local ktl = w).
  bf16x8 kOwn[3];
#pragma unroll
  for (int c = 0; c < 3; ++c) {
    FragU fk; fk.u[0] = 0; fk.u[1] = 0;
    const int tok = (c * 4 + w) * 16 + m;
    if (quad < 2 && tok < kN)
      fk.q = *(const uint4*)(kg + base + tok * 16 + quad * 8);
    kOwn[c] = fk.f;
  }

  // ---- Wm A-fragments with interleaved cat-dim mapping (unchanged).
  bf16x8 wmb[2];
#pragma unroll
  for (int kt = 0; kt < 2; ++kt) {
    FragU f;
#pragma unroll
    for (int j = 0; j < 8; ++j) {
      const int kdl = quad * 8 + j;
      const int orig = (kt * 2 + (kdl & 1)) * 16 + (kdl >> 1);
      f.h[j] = f2bf(Wm[m * 64 + orig]);
    }
    wmb[kt] = f.f;
  }
  const float4 bm4 = *(const float4*)(bm + quad * 4);

  __syncthreads();   // bar_a: vT staged

  bf16x8 vb[6];   // V B-frags
#pragma unroll
  for (int p = 0; p < 6; ++p) {
    FragU f;
    f.q = *(const uint4*)(s_vT + m * 200 + p * 32 + quad * 8);
    vb[p] = f.f;
  }
  __syncthreads();   // bar_a2: all vb reads done before S0 clobbers vT alias

  FragU onesU; onesU.u[0] = 0x3F803F803F803F80ULL; onesU.u[1] = onesU.u[0];
  const bf16x8 ones = onesU.f;
  const f32x4 zero4 = {0.f, 0.f, 0.f, 0.f};

  f32x4 o1[3], l1[3], o3[3], o4[3], o2[3], l2[3];
#pragma unroll
  for (int ti = 0; ti < 3; ++ti) {
    o1[ti] = zero4; l1[ti] = zero4; o3[ti] = zero4;
    o4[ti] = zero4; o2[ti] = zero4; l2[ti] = zero4;
  }

  // S_PHASE(CC): wave computes S for its own k-tile (CC*4+w) x all 12
  // q-tiles, loading each q B-fragment from global JUST BEFORE use (short
  // liveness; L2-hot). D lane(m,quad) reg r = S[q=qt*16+m][k=(CC*4+w)*16+
  // quad*4+r]. Writes: s_E[(qt*16+m)*72 + w*16+quad*4] (b64) + own-ET rows.
#define S_PHASE(CC)                                                           \
  do {                                                                        \
    _Pragma("unroll") for (int qt = 0; qt < 12; ++qt) {                       \
      FragU fq; fq.u[0] = 0; fq.u[1] = 0;                                     \
      const int tokq = qt * 16 + m;                                           \
      if (quad < 2 && tokq < kN)                                              \
        fq.q = *(const uint4*)(qg + base + tokq * 16 + quad * 8);             \
      f32x4 sv = MFMA(kOwn[CC], fq.f, zero4);                                 \
      const float e0 = exp2f(sv[0]), e1 = exp2f(sv[1]);                       \
      const float e2 = exp2f(sv[2]), e3 = exp2f(sv[3]);                       \
      uint2 evv;                                                              \
      evv.x = pack_trunc(e0, e1);                                             \
      evv.y = pack_trunc(e2, e3);                                             \
      *(uint2*)(s_E + (qt * 16 + m) * 72 + w * 16 + quad * 4) = evv;          \
      u16* etp = ET_w + (quad * 4) * 200 + qt * 16 + m;                       \
      etp[0]   = trunc_bf(e0);                                                \
      etp[200] = trunc_bf(e1);                                                \
      etp[400] = trunc_bf(e2);                                                \
      etp[600] = trunc_bf(e3);                                                \
    }                                                                         \
  } while (0)

  // ROW_PHASE(CC): o1/l1/o3/o4 for own q-tiles; s_E reads cross-wave (sealed
  // by barrier). arr3/arr4 loaded inline (TLP-hidden).
#define ROW_PHASE(CC)                                                         \
  _Pragma("unroll") for (int ti = 0; ti < 3; ++ti) {                          \
    const int qt = w + ti * 4;                                                \
    const u16* erp = s_E + (qt * 16 + m) * 72 + quad * 8;                     \
    _Pragma("unroll") for (int pl = 0; pl < 2; ++pl) {                        \
      const int pg = (CC) * 2 + pl;                                           \
      FragU pa; pa.q = *(const uint4*)(erp + pl * 32);                        \
      FragU a3; a3.q = *(const uint4*)(arr3 + (size_t)((qt * 6 + pg) * 64 + lane) * 8); \
      FragU a4; a4.q = *(const uint4*)(arr4 + (size_t)((qt * 6 + pg) * 64 + lane) * 8); \
      o1[ti] = MFMA(pa.f, vb[pg], o1[ti]);                                    \
      l1[ti] = MFMA(pa.f, ones, l1[ti]);                                      \
      o3[ti] = MFMA(a3.f, vb[pg], o3[ti]);                                    \
      o4[ti] = MFMA(a4.f, vb[pg], o4[ti]);                                    \
    }                                                                         \
  }

  // COL_PHASE(CC): reads OWN private ET (wave-local; no barrier needed).
  // Output key tile = CC*4+w, matching epilogue tt = w + CC*4.
#define COL_PHASE(CC)                                                         \
  {                                                                           \
    const u16* etr = ET_w + m * 200 + quad * 8;                               \
    _Pragma("unroll") for (int pg = 0; pg < 6; ++pg) {                        \
      FragU pT; pT.q = *(const uint4*)(etr + pg * 32);                        \
      o2[CC] = MFMA(pT.f, vb[pg], o2[CC]);                                    \
      l2[CC] = MFMA(pT.f, ones, l2[CC]);                                      \
    }                                                                         \
  }

  S_PHASE(0);
  __syncthreads();
  {
    COL_PHASE(0);
    ROW_PHASE(0);
  }
  __syncthreads();
  S_PHASE(1);
  __syncthreads();
  {
    COL_PHASE(1);
    ROW_PHASE(1);
  }
  __syncthreads();
  S_PHASE(2);
  __syncthreads();
  {
    COL_PHASE(2);
    ROW_PHASE(2);
  }

#undef S_PHASE
#undef ROW_PHASE
#undef COL_PHASE

  // ================= fused Wm epilogue (cat aliases own-ET; wave-local,
  // program-order after COL2's last own-ET read — no barrier needed) =======
  u16* cw = ET_w;
#pragma unroll
  for (int ti = 0; ti < 3; ++ti) {
    const int tt = w + ti * 4;
#pragma unroll
    for (int r = 0; r < 4; ++r) {
      const int token = quad * 4 + r;
      const float n1 = o1[ti][r] * __builtin_amdgcn_rcpf(l1[ti][r] - 8.0f);
      const float n2 = o2[ti][r] * __builtin_amdgcn_rcpf(l2[ti][r] - 8.0f);
      *(u32*)(cw + token * 72 + 2 * m)      = pack_bf2(n1, n2);       // dims 2m,2m+1
      *(u32*)(cw + token * 72 + 32 + 2 * m) = pack_bf2(o3[ti][r], o4[ti][r]);
    }
    f32x4 macc = {bm4.x, bm4.y, bm4.z, bm4.w};
#pragma unroll
    for (int kt = 0; kt < 2; ++kt) {
      FragU ca; ca.q = *(const uint4*)(cw + m * 72 + kt * 32 + quad * 8);
      macc = MFMA(wmb[kt], ca.f, macc);   // filt^T = Wm @ cat^T
    }
    if (tt * 16 + m < kN) {
      *(uint2*)(mg + base + (tt * 16 + m) * 16 + quad * 4) =
          make_uint2(pack_bf2(macc[0], macc[1]), pack_bf2(macc[2], macc[3]));
    }
  }
}

// ---------------------------------------------------------------------------
// Kernel 4: MFMA head-merge + Wo GEMM, fp32 out + bo (unchanged).
// ---------------------------------------------------------------------------
__global__ __launch_bounds__(256) void out_kernel(
    const u16* __restrict__ mg, const u16* __restrict__ wob,
    const float* __restrict__ bo, float* __restrict__ outg) {
  __shared__ u16 s_w[128 * 136];
  const int tid = threadIdx.x;
  {
    const uint4* src = (const uint4*)wob;
    for (int i = tid; i < 2048; i += 256) {
      const int row = i >> 4, q16 = i & 15;
      *(uint4*)(s_w + row * 136 + q16 * 8) = src[i];
    }
  }
  __syncthreads();

  const int w = tid >> 6, lane = tid & 63, quad = lane >> 4, m = lane & 15;
  const int r0 = blockIdx.x * 128;

  f32x4 acc0[8], acc1[8];
  const f32x4 z4 = {0.f, 0.f, 0.f, 0.f};
#pragma unroll
  for (int ct = 0; ct < 8; ++ct) { acc0[ct] = z4; acc1[ct] = z4; }

  const int hh = quad >> 1, hd8 = (quad & 1) * 8;
  const int ra = r0 + w * 16 + m;
  const int bt0 = ra / kN, n0 = ra - bt0 * kN;
  const int rb = ra + 64;
  const int bt1 = rb / kN, n1 = rb - bt1 * kN;
  const u16* mp0 = mg + ((size_t)(hh * kBT + bt0) * kN + n0) * 16 + hd8;
  const u16* mp1 = mg + ((size_t)(hh * kBT + bt1) * kN + n1) * 16 + hd8;
  const size_t hstep = (size_t)2 * kBT * kN * 16;

#pragma unroll
  for (int kp = 0; kp < 4; ++kp) {
    FragU a0; a0.q = *(const uint4*)(mp0 + kp * hstep);
    FragU a1; a1.q = *(const uint4*)(mp1 + kp * hstep);
#pragma unroll
    for (int ct = 0; ct < 8; ++ct) {
      FragU bfr; bfr.q = *(const uint4*)(s_w + (ct * 16 + m) * 136 + kp * 32 + quad * 8);
      acc0[ct] = MFMA(a0.f, bfr.f, acc0[ct]);
      acc1[ct] = MFMA(a1.f, bfr.f, acc1[ct]);
    }
  }

  float bc[8];
#pragma unroll
  for (int ct = 0; ct < 8; ++ct) bc[ct] = bo[ct * 16 + m];

#pragma unroll
  for (int half = 0; half < 2; ++half) {
    const f32x4* acc = half ? acc1 : acc0;
    const int rbase = r0 + (w + half * 4) * 16 + quad * 4;
#pragma unroll
    for (int rr = 0; rr < 4; ++rr) {
      float* op = outg + (size_t)(rbase + rr) * 128 + m;
#pragma unroll
      for (int ct = 0; ct < 8; ++ct)
        op[ct * 16] = acc[ct][rr] + bc[ct];
    }
  }
}

// ---------------------------------------------------------------------------
extern "C" void kernel_launch(void* const* d_in, const int* in_sizes, int n_in,
                              void* d_out, int out_size, void* d_ws, size_t ws_size,
                              hipStream_t stream) {
  const float* query = (const float*)d_in[0];
  const float* key   = (const float*)d_in[1];
  const float* value = (const float*)d_in[2];
  const float* Wq = (const float*)d_in[3];
  const float* bq = (const float*)d_in[4];
  const float* Wk = (const float*)d_in[5];
  const float* bk = (const float*)d_in[6];
  const float* Wv = (const float*)d_in[7];
  const float* bv = (const float*)d_in[8];
  const float* Wm = (const float*)d_in[9];
  const float* bm = (const float*)d_in[10];
  const float* Wo = (const float*)d_in[11];
  const float* bo = (const float*)d_in[12];
  const float* ne1 = (const float*)d_in[13];
  const float* ne2 = (const float*)d_in[14];

  const size_t tensor_bytes = (size_t)kH * kB * kT * kN * kHD * 2;  // 12,058,624
  const size_t frag_bytes = (size_t)12 * 6 * 64 * 8 * 2;            // 73,728
  char* ws = (char*)d_ws;
  u16* qs   = (u16*)(ws);                        // reused as m after attn
  u16* ks   = (u16*)(ws + tensor_bytes);
  u16* vs   = (u16*)(ws + 2 * tensor_bytes);
  u16* arr3 = (u16*)(ws + 3 * tensor_bytes);
  u16* arr4 = (u16*)(ws + 3 * tensor_bytes + frag_bytes);
  u16* wb   = (u16*)(ws + 3 * tensor_bytes + 2 * frag_bytes);  // 4x16384 bf16

  adp_kernel<<<12, 256, 0, stream>>>(ne1, ne2, arr3, arr4, Wq, Wk, Wv, Wo, wb);
  proj_kernel<<<dim3(kRows / 128, 3), 256, 0, stream>>>(
      query, key, value, wb, bq, bk, bv, qs, ks, vs);
  attn_kernel<<<kH * kB * kT, 256, 0, stream>>>(qs, ks, vs, arr3, arr4, Wm, bm, qs);
  out_kernel<<<kRows / 128, 256, 0, stream>>>(qs, wb + 49152, bo, (float*)d_out);
}

// Round 8
// 229.966 us; speedup vs baseline: 1.1940x; 1.1712x over previous
//
#include <hip/hip_runtime.h>

typedef unsigned int u32;
typedef unsigned short u16;
typedef unsigned long long ull;

constexpr int kB = 16, kT = 16, kN = 184, kD = 128, kH = 8, kHD = 16;
constexpr int kBT = kB * kT;            // 256
constexpr int kRows = kBT * kN;         // 47104
constexpr int kTile = kN * kHD;         // 2944 elements per (hb,t) tile
// softmax scale folded into q at projection: 0.25 * log2(e)
#define KQSCALE 0.36067376022224085f

typedef __attribute__((ext_vector_type(8))) short bf16x8;
typedef __attribute__((ext_vector_type(4))) float f32x4;

union FragU {
  bf16x8 f;
  ull u[2];
  uint4 q;
  u16 h[8];
};

#define MFMA(a, b, c) __builtin_amdgcn_mfma_f32_16x16x32_bf16((a), (b), (c), 0, 0, 0)

__device__ __forceinline__ float bf2f(u16 v) {
  return __uint_as_float(((u32)v) << 16);
}
__device__ __forceinline__ u16 f2bf(float f) {
  u32 x = __float_as_uint(f);
  x += 0x7fffu + ((x >> 16) & 1u);   // RNE
  return (u16)(x >> 16);
}
// pack two fp32 -> two bf16 (RNE) in one u32: lo in [15:0], hi in [31:16]
__device__ __forceinline__ u32 pack_bf2(float lo, float hi) {
  u32 a = __float_as_uint(lo); a += 0x7fffu + ((a >> 16) & 1u);
  u32 b = __float_as_uint(hi); b += 0x7fffu + ((b >> 16) & 1u);
  return __builtin_amdgcn_perm(b, a, 0x07060302);
}
// pack two fp32 -> two bf16 (truncate) in one u32 — single v_perm
__device__ __forceinline__ u32 pack_trunc(float lo, float hi) {
  return __builtin_amdgcn_perm(__float_as_uint(hi), __float_as_uint(lo), 0x07060302);
}
__device__ __forceinline__ u16 trunc_bf(float f) {
  return (u16)(__float_as_uint(f) >> 16);
}

// ---------------------------------------------------------------------------
// Kernel A (merged): blockIdx.y 0..2 = q/k/v projection GEMM (W converted
// fp32->bf16 inline while staging — wcvt launch eliminated); blockIdx.y == 3,
// blockIdx.x < 12 = adp softmax fragments (runs CONCURRENTLY with proj — no
// data dependency: adp writes arr3/arr4 (read only by attn, next launch);
// proj reads only q/k/v/W/b). One 69,632 B LDS pool shared by both roles.
// ---------------------------------------------------------------------------
__global__ __launch_bounds__(256) void proj_kernel(
    const float* __restrict__ qin, const float* __restrict__ kin, const float* __restrict__ vin,
    const float* __restrict__ Wq, const float* __restrict__ Wk, const float* __restrict__ Wv,
    const float* __restrict__ bq, const float* __restrict__ bk, const float* __restrict__ bv,
    u16* __restrict__ qo, u16* __restrict__ ko, u16* __restrict__ vo,
    const float* __restrict__ ne1, const float* __restrict__ ne2,
    u16* __restrict__ arr3, u16* __restrict__ arr4) {
  __shared__ float smem_f[17408];          // 69,632 B pool
  const int tid = threadIdx.x;

  if (blockIdx.y == 3) {
    // ================= adp role (12 blocks) =================
    if (blockIdx.x >= 12) return;
    float* const s1  = smem_f;             // [kN*10]
    float* const s2  = smem_f + 1840;      // [10*kN]
    float* const l1r = smem_f + 3680;      // [kN]
    float* const l2c = smem_f + 3864;      // [kN]

    for (int i = tid; i < kN * 10; i += 256) { s1[i] = ne1[i]; s2[i] = ne2[i]; }
    __syncthreads();

    if (tid < kN) {
      const int r = tid;
      float reg[10];
#pragma unroll
      for (int e = 0; e < 10; ++e) reg[e] = s1[r * 10 + e];
      float sum = 0.f;
      for (int c = 0; c < kN; ++c) {
        float d = 0.f;
#pragma unroll
        for (int e = 0; e < 10; ++e) d += reg[e] * s2[e * kN + c];
        sum += __expf(d);
      }
      l1r[r] = sum;

      const int c = tid;
      float regc[10];
#pragma unroll
      for (int e = 0; e < 10; ++e) regc[e] = s2[e * kN + c];
      sum = 0.f;
      for (int r2 = 0; r2 < kN; ++r2) {
        float d = 0.f;
#pragma unroll
        for (int e = 0; e < 10; ++e) d += s1[r2 * 10 + e] * regc[e];
        sum += __expf(d);
      }
      l2c[c] = sum;
    }
    __syncthreads();

    for (int ee = blockIdx.x * 256 + tid; ee < 12 * 6 * 64; ee += 12 * 256) {
      const int i = ee / 384;
      const int rem = ee - i * 384;
      const int p = rem >> 6;
      const int lane = rem & 63;
      const int row = i * 16 + (lane & 15);
      const int cb = p * 32 + (lane >> 4) * 8;
      FragU fo3, fo4;
      const bool rok = row < kN;
      float inv1 = 0.f, inv2 = 0.f;
      float rreg[10], creg[10];
      if (rok) {
        inv1 = 1.f / l1r[row];
        inv2 = 1.f / l2c[row];
#pragma unroll
        for (int e = 0; e < 10; ++e) {
          rreg[e] = s1[row * 10 + e];
          creg[e] = s2[e * kN + row];
        }
      }
#pragma unroll
      for (int j = 0; j < 8; ++j) {
        const int col = cb + j;
        float v3 = 0.f, v4 = 0.f;
        if (rok && col < kN) {
          float d3 = 0.f, d4 = 0.f;
#pragma unroll
          for (int e = 0; e < 10; ++e) {
            d3 += rreg[e] * s2[e * kN + col];
            d4 += s1[col * 10 + e] * creg[e];
          }
          v3 = __expf(d3) * inv1;
          v4 = __expf(d4) * inv2;
        }
        fo3.h[j] = f2bf(v3);
        fo4.h[j] = f2bf(v4);
      }
      *(uint4*)(arr3 + (size_t)ee * 8) = fo3.q;
      *(uint4*)(arr4 + (size_t)ee * 8) = fo4.q;
    }
    return;
  }

  // ================= projection role =================
  u16* const s_w = (u16*)smem_f;           // [128][136]
  u16* const s_a = (u16*)smem_f + 128 * 136;

  const float* in; const float* Wf; const float* bias; u16* out; float scale;
  if (blockIdx.y == 0)      { in = qin; Wf = Wq; bias = bq; out = qo; scale = KQSCALE; }
  else if (blockIdx.y == 1) { in = kin; Wf = Wk; bias = bk; out = ko; scale = 1.f; }
  else                      { in = vin; Wf = Wv; bias = bv; out = vo; scale = 1.f; }

  const int r0 = blockIdx.x * 128;
  {
    // stage W (fp32 -> bf16 RNE inline; same [row][col8] -> row*136 layout)
    for (int i = tid; i < 2048; i += 256) {
      const int row = i >> 4, c8 = (i & 15) * 8;
      const float4 w0 = *(const float4*)(Wf + row * 128 + c8);
      const float4 w1 = *(const float4*)(Wf + row * 128 + c8 + 4);
      *(uint4*)(s_w + row * 136 + c8) =
          make_uint4(pack_bf2(w0.x, w0.y), pack_bf2(w0.z, w0.w),
                     pack_bf2(w1.x, w1.y), pack_bf2(w1.z, w1.w));
    }
    // stage A-tile (coalesced float4, bf16 RNE)
    const float* abase = in + (size_t)r0 * 128;
#pragma unroll
    for (int i = 0; i < 16; ++i) {
      const int idx = i * 1024 + tid * 4;
      const float4 v = *(const float4*)(abase + idx);
      const int row = idx >> 7, col = idx & 127;
      *(u32*)(s_a + row * 136 + col)     = pack_bf2(v.x, v.y);
      *(u32*)(s_a + row * 136 + col + 2) = pack_bf2(v.z, v.w);
    }
  }
  __syncthreads();

  const int w = tid >> 6, lane = tid & 63, quad = lane >> 4, m = lane & 15;

  f32x4 acc0[8], acc1[8];
  const f32x4 z4 = {0.f, 0.f, 0.f, 0.f};
#pragma unroll
  for (int ct = 0; ct < 8; ++ct) { acc0[ct] = z4; acc1[ct] = z4; }

  const u16* ap0 = s_a + (w * 16 + m) * 136 + quad * 8;
  const u16* ap1 = ap0 + 64 * 136;

#pragma unroll
  for (int kp = 0; kp < 4; ++kp) {
    FragU a0; a0.q = *(const uint4*)(ap0 + kp * 32);
    FragU a1; a1.q = *(const uint4*)(ap1 + kp * 32);
#pragma unroll
    for (int ct = 0; ct < 8; ++ct) {
      FragU bfr; bfr.q = *(const uint4*)(s_w + (ct * 16 + m) * 136 + kp * 32 + quad * 8);
      acc0[ct] = MFMA(a0.f, bfr.f, acc0[ct]);
      acc1[ct] = MFMA(a1.f, bfr.f, acc1[ct]);
    }
  }

  float bc[8];
#pragma unroll
  for (int ct = 0; ct < 8; ++ct) bc[ct] = bias[ct * 16 + m];

#pragma unroll
  for (int half = 0; half < 2; ++half) {
    const f32x4* acc = half ? acc1 : acc0;
    const int rbase = r0 + (w + half * 4) * 16 + quad * 4;
#pragma unroll
    for (int rr = 0; rr < 4; ++rr) {
      const int r = rbase + rr;
      const int bt = r / kN;
      const int n = r - bt * kN;
      u16* op = out + ((size_t)bt * kN + n) * 16 + m;
#pragma unroll
      for (int ct = 0; ct < 8; ++ct)
        op[(size_t)ct * kBT * kN * 16] = f2bf((acc[ct][rr] + bc[ct]) * scale);
    }
  }
}

// ---------------------------------------------------------------------------
// Kernel 3: MFMA dual-softmax attention + adp mixing + fused Wm.
// r11 version verbatim (verified: 63.0 us, absmax 2e-3, no spill).
//  * E = exp2(S) computed once; ROW pass wave-local on s_E (no barrier),
//    COL pass on double-buffered s_ET; 4-barrier overlapped schedule with
//    interval body {LOAD_ARR(c), COL(c), ROW(c), S(c+1)} (ROW reads s_E
//    before S overwrites — WAR order).
//  * LDS pool 78,848 B (2 blocks/CU); s_vT/s_cat alias ET1 across barriers.
// ---------------------------------------------------------------------------
__global__ __launch_bounds__(256, 2) void attn_kernel(
    const u16* qg, const u16* __restrict__ kg, const u16* __restrict__ vg,
    const u16* __restrict__ arr3, const u16* __restrict__ arr4,
    const float* __restrict__ Wm, const float* __restrict__ bm,
    u16* mg) {
  __shared__ u16 pool[39424];              // 78848 B total
  u16* const s_E   = pool;                 // [192][72]  (13824 elems)
  u16* const s_ET0 = pool + 13824;         // [64][200]  (12800 elems)
  u16* const s_ET1 = pool + 26624;         // [64][200]  (12800 elems)
  u16* const s_vT  = s_ET1;                // alias: [16][200] (3200 elems)
  u16* const s_cat = s_ET1;                // alias: 4*1152 = 4608 elems

  const int tid = threadIdx.x;
  const size_t base = (size_t)blockIdx.x * kTile;
  const int w = tid >> 6, lane = tid & 63;
  const int quad = lane >> 4, m = lane & 15;

  // ---- stage V transposed into s_vT (= ET1 region; dead after vb reads)
  for (int idx = tid; idx < 3072; idx += 256) {
    const int t = idx >> 4, ch = idx & 15;
    s_vT[ch * 200 + t] = (t < kN) ? vg[base + idx] : (u16)0;
  }

  // ---- K A-fragments (rows = k tokens) for ALL 12 k-tiles, from global.
  bf16x8 kfr[12];
#pragma unroll
  for (int t12 = 0; t12 < 12; ++t12) {
    FragU fk; fk.u[0] = 0; fk.u[1] = 0;
    const int tok = t12 * 16 + m;
    if (quad < 2 && tok < kN)
      fk.q = *(const uint4*)(kg + base + tok * 16 + quad * 8);
    kfr[t12] = fk.f;
  }
  // ---- Q B-fragments for this wave's own 3 q-tiles {w, w+4, w+8}.
  bf16x8 qB[3];
#pragma unroll
  for (int ti = 0; ti < 3; ++ti) {
    FragU fq; fq.u[0] = 0; fq.u[1] = 0;
    const int tok = (w + ti * 4) * 16 + m;
    if (quad < 2 && tok < kN)
      fq.q = *(const uint4*)(qg + base + tok * 16 + quad * 8);
    qB[ti] = fq.f;
  }

  // ---- Wm A-fragments with interleaved cat-dim mapping (unchanged).
  bf16x8 wmb[2];
#pragma unroll
  for (int kt = 0; kt < 2; ++kt) {
    FragU f;
#pragma unroll
    for (int j = 0; j < 8; ++j) {
      const int kdl = quad * 8 + j;
      const int orig = (kt * 2 + (kdl & 1)) * 16 + (kdl >> 1);
      f.h[j] = f2bf(Wm[m * 64 + orig]);
    }
    wmb[kt] = f.f;
  }
  const float4 bm4 = *(const float4*)(bm + quad * 4);

  // bar_a: s_vT ready AND all waves' qg reads drained (mg aliases qg; mg
  // writes happen only after bar3).
  __syncthreads();

  bf16x8 vb[6];   // V B-frags: B[token][ch]
#pragma unroll
  for (int p = 0; p < 6; ++p) {
    FragU f;
    f.q = *(const uint4*)(s_vT + m * 200 + p * 32 + quad * 8);
    vb[p] = f.f;
  }
  FragU onesU; onesU.u[0] = 0x3F803F803F803F80ULL; onesU.u[1] = onesU.u[0];
  const bf16x8 ones = onesU.f;
  const f32x4 zero4 = {0.f, 0.f, 0.f, 0.f};

  f32x4 o1[3], l1[3], o3[3], o4[3], o2[3], l2[3];
#pragma unroll
  for (int ti = 0; ti < 3; ++ti) {
    o1[ti] = zero4; l1[ti] = zero4; o3[ti] = zero4;
    o4[ti] = zero4; o2[ti] = zero4; l2[ti] = zero4;
  }

  // S_PHASE(CC, ETB): wave computes its 3 q-tiles x 4 k-tiles of E = exp2(S),
  // stores as b64 into s_E rows (own rows, wave-local) + b16 scatter into ETB.
#define S_PHASE(CC, ETB)                                                      \
  do {                                                                        \
    _Pragma("unroll") for (int ti = 0; ti < 3; ++ti) {                        \
      const int qt = w + ti * 4;                                              \
      const int qrow = qt * 16 + m;                                           \
      _Pragma("unroll") for (int ktl = 0; ktl < 4; ++ktl) {                   \
        f32x4 sv = MFMA(kfr[(CC) * 4 + ktl], qB[ti], zero4);                  \
        const float e0 = exp2f(sv[0]), e1 = exp2f(sv[1]);                     \
        const float e2 = exp2f(sv[2]), e3 = exp2f(sv[3]);                     \
        uint2 ev;                                                             \
        ev.x = pack_trunc(e0, e1);                                            \
        ev.y = pack_trunc(e2, e3);                                            \
        *(uint2*)(s_E + qrow * 72 + ktl * 16 + quad * 4) = ev;                \
        u16* etp = (ETB) + (ktl * 16 + quad * 4) * 200 + qrow;                \
        etp[0]   = trunc_bf(e0);                                              \
        etp[200] = trunc_bf(e1);                                              \
        etp[400] = trunc_bf(e2);                                              \
        etp[600] = trunc_bf(e3);                                              \
      }                                                                       \
    }                                                                         \
  } while (0)

#define LOAD_ARR(CC)                                                          \
  _Pragma("unroll") for (int ti = 0; ti < 3; ++ti) {                          \
    const int qt = w + ti * 4;                                                \
    _Pragma("unroll") for (int pl = 0; pl < 2; ++pl) {                        \
      const int pg = (CC) * 2 + pl;                                           \
      a3f[ti * 2 + pl].q = *(const uint4*)(arr3 + (size_t)((qt * 6 + pg) * 64 + lane) * 8); \
      a4f[ti * 2 + pl].q = *(const uint4*)(arr4 + (size_t)((qt * 6 + pg) * 64 + lane) * 8); \
    }                                                                         \
  }

  // ROW_PHASE(CC): reads own s_E rows (wave-local; no barrier dependency).
#define ROW_PHASE(CC)                                                         \
  _Pragma("unroll") for (int ti = 0; ti < 3; ++ti) {                          \
    const int qt = w + ti * 4;                                                \
    const u16* erp = s_E + (qt * 16 + m) * 72 + quad * 8;                     \
    _Pragma("unroll") for (int pl = 0; pl < 2; ++pl) {                        \
      const int pg = (CC) * 2 + pl;                                           \
      FragU pa; pa.q = *(const uint4*)(erp + pl * 32);                        \
      o1[ti] = MFMA(pa.f, vb[pg], o1[ti]);                                    \
      l1[ti] = MFMA(pa.f, ones, l1[ti]);                                      \
      o3[ti] = MFMA(a3f[ti * 2 + pl].f, vb[pg], o3[ti]);                      \
      o4[ti] = MFMA(a4f[ti * 2 + pl].f, vb[pg], o4[ti]);                      \
    }                                                                         \
  }

  // COL_PHASE(CC, ETB): reads E^T rows (cross-wave; requires barrier).
#define COL_PHASE(CC, ETB)                                                    \
  {                                                                           \
    const u16* etr = (ETB) + (w * 16 + m) * 200 + quad * 8;                   \
    _Pragma("unroll") for (int pg = 0; pg < 6; ++pg) {                        \
      FragU pT; pT.q = *(const uint4*)(etr + pg * 32);                        \
      o2[CC] = MFMA(pT.f, vb[pg], o2[CC]);                                    \
      l2[CC] = MFMA(pT.f, ones, l2[CC]);                                      \
    }                                                                         \
  }

  // ---- I0: produce chunk 0
  S_PHASE(0, s_ET0);
  __syncthreads();   // bar1: ET0 sealed; vb reads sealed before S1 hits ET1
  // ---- I1: consume chunk 0, produce chunk 1 (ROW0 reads s_E BEFORE S1
  //          overwrites it — order matters)
  {
    FragU a3f[6], a4f[6];
    LOAD_ARR(0);
    COL_PHASE(0, s_ET0);
    ROW_PHASE(0);
    S_PHASE(1, s_ET1);
  }
  __syncthreads();   // bar2: ET1 sealed; COL0 done with ET0
  // ---- I2
  {
    FragU a3f[6], a4f[6];
    LOAD_ARR(1);
    COL_PHASE(1, s_ET1);
    ROW_PHASE(1);
    S_PHASE(2, s_ET0);
  }
  __syncthreads();   // bar3: ET0 sealed; COL1 done with ET1 (cat may reuse)
  // ---- I3
  {
    FragU a3f[6], a4f[6];
    LOAD_ARR(2);
    COL_PHASE(2, s_ET0);
    ROW_PHASE(2);
  }

#undef S_PHASE
#undef LOAD_ARR
#undef ROW_PHASE
#undef COL_PHASE

  // ================= fused Wm epilogue (per own tile) =================
  u16* cw = s_cat + w * 1152;
#pragma unroll
  for (int ti = 0; ti < 3; ++ti) {
    const int tt = w + ti * 4;
#pragma unroll
    for (int r = 0; r < 4; ++r) {
      const int token = quad * 4 + r;
      const float n1 = o1[ti][r] * __builtin_amdgcn_rcpf(l1[ti][r] - 8.0f);
      const float n2 = o2[ti][r] * __builtin_amdgcn_rcpf(l2[ti][r] - 8.0f);
      *(u32*)(cw + token * 72 + 2 * m)      = pack_bf2(n1, n2);       // dims 2m,2m+1
      *(u32*)(cw + token * 72 + 32 + 2 * m) = pack_bf2(o3[ti][r], o4[ti][r]);
    }
    f32x4 macc = {bm4.x, bm4.y, bm4.z, bm4.w};
#pragma unroll
    for (int kt = 0; kt < 2; ++kt) {
      FragU ca; ca.q = *(const uint4*)(cw + m * 72 + kt * 32 + quad * 8);
      macc = MFMA(wmb[kt], ca.f, macc);   // filt^T = Wm @ cat^T
    }
    if (tt * 16 + m < kN) {
      *(uint2*)(mg + base + (tt * 16 + m) * 16 + quad * 4) =
          make_uint2(pack_bf2(macc[0], macc[1]), pack_bf2(macc[2], macc[3]));
    }
  }
}

// ---------------------------------------------------------------------------
// Kernel 4: MFMA head-merge + Wo GEMM, fp32 out + bo. r15: Wo staged from
// fp32 directly (inline RNE conversion — wcvt dependency removed).
// ---------------------------------------------------------------------------
__global__ __launch_bounds__(256) void out_kernel(
    const u16* __restrict__ mg, const float* __restrict__ Wo,
    const float* __restrict__ bo, float* __restrict__ outg) {
  __shared__ u16 s_w[128 * 136];
  const int tid = threadIdx.x;
  {
    for (int i = tid; i < 2048; i += 256) {
      const int row = i >> 4, c8 = (i & 15) * 8;
      const float4 w0 = *(const float4*)(Wo + row * 128 + c8);
      const float4 w1 = *(const float4*)(Wo + row * 128 + c8 + 4);
      *(uint4*)(s_w + row * 136 + c8) =
          make_uint4(pack_bf2(w0.x, w0.y), pack_bf2(w0.z, w0.w),
                     pack_bf2(w1.x, w1.y), pack_bf2(w1.z, w1.w));
    }
  }
  __syncthreads();

  const int w = tid >> 6, lane = tid & 63, quad = lane >> 4, m = lane & 15;
  const int r0 = blockIdx.x * 128;

  f32x4 acc0[8], acc1[8];
  const f32x4 z4 = {0.f, 0.f, 0.f, 0.f};
#pragma unroll
  for (int ct = 0; ct < 8; ++ct) { acc0[ct] = z4; acc1[ct] = z4; }

  const int hh = quad >> 1, hd8 = (quad & 1) * 8;
  const int ra = r0 + w * 16 + m;
  const int bt0 = ra / kN, n0 = ra - bt0 * kN;
  const int rb = ra + 64;
  const int bt1 = rb / kN, n1 = rb - bt1 * kN;
  const u16* mp0 = mg + ((size_t)(hh * kBT + bt0) * kN + n0) * 16 + hd8;
  const u16* mp1 = mg + ((size_t)(hh * kBT + bt1) * kN + n1) * 16 + hd8;
  const size_t hstep = (size_t)2 * kBT * kN * 16;

#pragma unroll
  for (int kp = 0; kp < 4; ++kp) {
    FragU a0; a0.q = *(const uint4*)(mp0 + kp * hstep);
    FragU a1; a1.q = *(const uint4*)(mp1 + kp * hstep);
#pragma unroll
    for (int ct = 0; ct < 8; ++ct) {
      FragU bfr; bfr.q = *(const uint4*)(s_w + (ct * 16 + m) * 136 + kp * 32 + quad * 8);
      acc0[ct] = MFMA(a0.f, bfr.f, acc0[ct]);
      acc1[ct] = MFMA(a1.f, bfr.f, acc1[ct]);
    }
  }

  float bc[8];
#pragma unroll
  for (int ct = 0; ct < 8; ++ct) bc[ct] = bo[ct * 16 + m];

#pragma unroll
  for (int half = 0; half < 2; ++half) {
    const f32x4* acc = half ? acc1 : acc0;
    const int rbase = r0 + (w + half * 4) * 16 + quad * 4;
#pragma unroll
    for (int rr = 0; rr < 4; ++rr) {
      float* op = outg + (size_t)(rbase + rr) * 128 + m;
#pragma unroll
      for (int ct = 0; ct < 8; ++ct)
        op[ct * 16] = acc[ct][rr] + bc[ct];
    }
  }
}

// ---------------------------------------------------------------------------
extern "C" void kernel_launch(void* const* d_in, const int* in_sizes, int n_in,
                              void* d_out, int out_size, void* d_ws, size_t ws_size,
                              hipStream_t stream) {
  const float* query = (const float*)d_in[0];
  const float* key   = (const float*)d_in[1];
  const float* value = (const float*)d_in[2];
  const float* Wq = (const float*)d_in[3];
  const float* bq = (const float*)d_in[4];
  const float* Wk = (const float*)d_in[5];
  const float* bk = (const float*)d_in[6];
  const float* Wv = (const float*)d_in[7];
  const float* bv = (const float*)d_in[8];
  const float* Wm = (const float*)d_in[9];
  const float* bm = (const float*)d_in[10];
  const float* Wo = (const float*)d_in[11];
  const float* bo = (const float*)d_in[12];
  const float* ne1 = (const float*)d_in[13];
  const float* ne2 = (const float*)d_in[14];

  const size_t tensor_bytes = (size_t)kH * kB * kT * kN * kHD * 2;  // 12,058,624
  const size_t frag_bytes = (size_t)12 * 6 * 64 * 8 * 2;            // 73,728
  char* ws = (char*)d_ws;
  u16* qs   = (u16*)(ws);                        // reused as m after attn
  u16* ks   = (u16*)(ws + tensor_bytes);
  u16* vs   = (u16*)(ws + 2 * tensor_bytes);
  u16* arr3 = (u16*)(ws + 3 * tensor_bytes);
  u16* arr4 = (u16*)(ws + 3 * tensor_bytes + frag_bytes);

  proj_kernel<<<dim3(kRows / 128, 4), 256, 0, stream>>>(
      query, key, value, Wq, Wk, Wv, bq, bk, bv, qs, ks, vs,
      ne1, ne2, arr3, arr4);
  attn_kernel<<<kH * kB * kT, 256, 0, stream>>>(qs, ks, vs, arr3, arr4, Wm, bm, qs);
  out_kernel<<<kRows / 128, 256, 0, stream>>>(qs, Wo, bo, (float*)d_out);
}